// Round 3
// baseline (548.267 us; speedup 1.0000x reference)
//
#include <hip/hip_runtime.h>

#define LEVEL_DIM 8
#define CDIM 32                 // bin grid resolution per axis
#define NCELLS (CDIM*CDIM*CDIM) // 32768 bins

typedef float f32x4 __attribute__((ext_vector_type(4)));

__device__ __forceinline__ int cell_of(float x, float y, float z) {
    int cx = min(CDIM - 1, max(0, (int)(x * (float)CDIM)));
    int cy = min(CDIM - 1, max(0, (int)(y * (float)CDIM)));
    int cz = min(CDIM - 1, max(0, (int)(z * (float)CDIM)));
    return cx + (cy << 5) + (cz << 10);
}

__global__ __launch_bounds__(256) void nv_hist(
    const float* __restrict__ in, int* __restrict__ hist, int B)
{
    const int b = blockIdx.x * 256 + threadIdx.x;
    if (b >= B) return;
    const float x = in[3 * b], y = in[3 * b + 1], z = in[3 * b + 2];
    atomicAdd(&hist[cell_of(x, y, z)], 1);
}

// in-place exclusive scan of NCELLS ints, single workgroup
__global__ __launch_bounds__(1024) void nv_scan(int* __restrict__ cell)
{
    __shared__ int lds[1024];
    const int tid = threadIdx.x;
    const int base = tid * (NCELLS / 1024);   // 32 per thread
    int v[NCELLS / 1024];
    int s = 0;
    #pragma unroll
    for (int e = 0; e < NCELLS / 1024; ++e) { v[e] = cell[base + e]; s += v[e]; }
    lds[tid] = s;
    __syncthreads();
    for (int off = 1; off < 1024; off <<= 1) {
        int t = 0;
        if (tid >= off) t = lds[tid - off];
        __syncthreads();
        if (tid >= off) lds[tid] += t;
        __syncthreads();
    }
    int run = lds[tid] - s;   // exclusive prefix for this thread's chunk
    #pragma unroll
    for (int e = 0; e < NCELLS / 1024; ++e) { cell[base + e] = run; run += v[e]; }
}

__global__ __launch_bounds__(256) void nv_scatter(
    const float* __restrict__ in, int* __restrict__ offs,
    float4* __restrict__ sorted, int B)
{
    const int b = blockIdx.x * 256 + threadIdx.x;
    if (b >= B) return;
    const float x = in[3 * b], y = in[3 * b + 1], z = in[3 * b + 2];
    const int pos = atomicAdd(&offs[cell_of(x, y, z)], 1);
    sorted[pos] = make_float4(x, y, z, __uint_as_float((unsigned)b));
}

template<bool SORTED>
__global__ __launch_bounds__(256) void nv_encode_kernel(
    const float* __restrict__ in,          // raw coords (direct path)
    const float4* __restrict__ sorted,     // sorted coords+idx (binned path)
    const float* __restrict__ emb,
    float* __restrict__ out,
    int B, int chunks_per_xcd)
{
    // XCD-contiguous swizzle: XCD k gets a contiguous range of sorted order
    int blk = blockIdx.x;
    if (chunks_per_xcd > 0) blk = (blk & 7) * chunks_per_xcd + (blk >> 3);
    const int i = blk * 256 + threadIdx.x;
    if (i >= B) return;

    float x, y, z;
    unsigned ob;
    if (SORTED) {
        const float4 s = sorted[i];
        x = s.x; y = s.y; z = s.z; ob = __float_as_uint(s.w);
    } else {
        x = in[3 * i]; y = in[3 * i + 1]; z = in[3 * i + 2];
        ob = (unsigned)i;
    }

    float* op = out + (size_t)ob * 32;

    const int RES[4] = {16, 32, 64, 128};
    const int OFF[4] = {0, 4096, 36864, 299008};

    #pragma unroll
    for (int l = 0; l < 4; ++l) {
        const int R = RES[l];
        const float scale = (float)(R - 1);

        const float px = x * scale, py = y * scale, pz = z * scale;
        const float gx = floorf(px), gy = floorf(py), gz = floorf(pz);
        const float fx = px - gx, fy = py - gy, fz = pz - gz;
        const int ix = (int)gx, iy = (int)gy, iz = (int)gz;

        const int ix0 = min(max(ix, 0), R - 1);
        const int ix1 = min(max(ix + 1, 0), R - 1);
        const int iy0 = min(max(iy, 0), R - 1);
        const int iy1 = min(max(iy + 1, 0), R - 1);
        const int iz0 = min(max(iz, 0), R - 1);
        const int iz1 = min(max(iz + 1, 0), R - 1);

        const float* tbl = emb + (size_t)OFF[l] * LEVEL_DIM;
        const float wx0 = 1.0f - fx, wx1 = fx;

        float acc[8];
        #pragma unroll
        for (int c = 0; c < 8; ++c) acc[c] = 0.0f;

        #pragma unroll
        for (int kk = 0; kk < 2; ++kk) {
            const int   zz = kk ? iz1 : iz0;
            const float wz = kk ? fz : (1.0f - fz);
            #pragma unroll
            for (int jj = 0; jj < 2; ++jj) {
                const int   yy = jj ? iy1 : iy0;
                const float wy = jj ? fy : (1.0f - fy);

                const size_t rowbase = ((size_t)zz * R + yy) * (size_t)R;
                const float* r0 = tbl + (rowbase + ix0) * LEVEL_DIM;
                const float* r1 = tbl + (rowbase + ix1) * LEVEL_DIM;

                const float w0 = (wx0 * wy) * wz;
                const float w1 = (wx1 * wy) * wz;

                const float4 a0 = *(const float4*)(r0);
                const float4 a1 = *(const float4*)(r0 + 4);
                const float4 b0 = *(const float4*)(r1);
                const float4 b1 = *(const float4*)(r1 + 4);

                acc[0] = fmaf(w0, a0.x, acc[0]); acc[1] = fmaf(w0, a0.y, acc[1]);
                acc[2] = fmaf(w0, a0.z, acc[2]); acc[3] = fmaf(w0, a0.w, acc[3]);
                acc[4] = fmaf(w0, a1.x, acc[4]); acc[5] = fmaf(w0, a1.y, acc[5]);
                acc[6] = fmaf(w0, a1.z, acc[6]); acc[7] = fmaf(w0, a1.w, acc[7]);

                acc[0] = fmaf(w1, b0.x, acc[0]); acc[1] = fmaf(w1, b0.y, acc[1]);
                acc[2] = fmaf(w1, b0.z, acc[2]); acc[3] = fmaf(w1, b0.w, acc[3]);
                acc[4] = fmaf(w1, b1.x, acc[4]); acc[5] = fmaf(w1, b1.y, acc[5]);
                acc[6] = fmaf(w1, b1.z, acc[6]); acc[7] = fmaf(w1, b1.w, acc[7]);
            }
        }

        // nontemporal: streaming output, keep L2 for the tables
        f32x4 lo = { acc[0], acc[1], acc[2], acc[3] };
        f32x4 hi = { acc[4], acc[5], acc[6], acc[7] };
        __builtin_nontemporal_store(lo, (f32x4*)(op + l * 8));
        __builtin_nontemporal_store(hi, (f32x4*)(op + l * 8 + 4));
    }
}

extern "C" void kernel_launch(void* const* d_in, const int* in_sizes, int n_in,
                              void* d_out, int out_size, void* d_ws, size_t ws_size,
                              hipStream_t stream) {
    const float* in  = (const float*)d_in[0];
    const float* emb = (const float*)d_in[1];
    float* out = (float*)d_out;

    const int B = in_sizes[0] / 3;
    const int block = 256;
    const int grid = (B + block - 1) / block;

    const size_t hist_bytes = (size_t)NCELLS * sizeof(int);   // 128 KiB
    const size_t need = hist_bytes + (size_t)B * sizeof(float4);

    if (ws_size >= need) {
        int*    hist   = (int*)d_ws;
        float4* sorted = (float4*)((char*)d_ws + hist_bytes);

        (void)hipMemsetAsync(hist, 0, hist_bytes, stream);
        nv_hist<<<grid, block, 0, stream>>>(in, hist, B);
        nv_scan<<<1, 1024, 0, stream>>>(hist);
        nv_scatter<<<grid, block, 0, stream>>>(in, hist, sorted, B);

        const int chunks = (grid % 8 == 0) ? grid / 8 : 0;
        nv_encode_kernel<true><<<grid, block, 0, stream>>>(
            in, sorted, emb, out, B, chunks);
    } else {
        nv_encode_kernel<false><<<grid, block, 0, stream>>>(
            in, (const float4*)nullptr, emb, out, B, 0);
    }
}

// Round 4
// 328.367 us; speedup vs baseline: 1.6697x; 1.6697x over previous
//
#include <hip/hip_runtime.h>

#define LEVEL_DIM 8
#define CDIM 32                 // bin grid resolution per axis
#define NCELLS (CDIM*CDIM*CDIM) // 32768 bins
#define LDS_ROWS 334            // 27 + 27 + 64 + 216 staged rows

typedef float f32x4 __attribute__((ext_vector_type(4)));

__device__ __forceinline__ int cell_of(float x, float y, float z) {
    int cx = min(CDIM - 1, max(0, (int)(x * (float)CDIM)));
    int cy = min(CDIM - 1, max(0, (int)(y * (float)CDIM)));
    int cz = min(CDIM - 1, max(0, (int)(z * (float)CDIM)));
    return cx + (cy << 5) + (cz << 10);
}

__global__ __launch_bounds__(256) void nv_hist(
    const float* __restrict__ in, int* __restrict__ hist, int B)
{
    const int b = blockIdx.x * 256 + threadIdx.x;
    if (b >= B) return;
    const float x = in[3 * b], y = in[3 * b + 1], z = in[3 * b + 2];
    atomicAdd(&hist[cell_of(x, y, z)], 1);
}

// in-place exclusive scan of NCELLS ints, single workgroup
__global__ __launch_bounds__(1024) void nv_scan(int* __restrict__ cell)
{
    __shared__ int lds[1024];
    const int tid = threadIdx.x;
    const int base = tid * (NCELLS / 1024);   // 32 per thread
    int v[NCELLS / 1024];
    int s = 0;
    #pragma unroll
    for (int e = 0; e < NCELLS / 1024; ++e) { v[e] = cell[base + e]; s += v[e]; }
    lds[tid] = s;
    __syncthreads();
    for (int off = 1; off < 1024; off <<= 1) {
        int t = 0;
        if (tid >= off) t = lds[tid - off];
        __syncthreads();
        if (tid >= off) lds[tid] += t;
        __syncthreads();
    }
    int run = lds[tid] - s;   // exclusive prefix for this thread's chunk
    #pragma unroll
    for (int e = 0; e < NCELLS / 1024; ++e) { cell[base + e] = run; run += v[e]; }
}

__global__ __launch_bounds__(256) void nv_scatter(
    const float* __restrict__ in, int* __restrict__ offs,
    float4* __restrict__ sorted, int B)
{
    const int b = blockIdx.x * 256 + threadIdx.x;
    if (b >= B) return;
    const float x = in[3 * b], y = in[3 * b + 1], z = in[3 * b + 2];
    const int pos = atomicAdd(&offs[cell_of(x, y, z)], 1);
    sorted[pos] = make_float4(x, y, z, __uint_as_float((unsigned)b));
}

// ---- cell-based encode: stage per-cell table slabs into LDS, gather from LDS ----
// level geometry: span S per axis covers every grid point a cell can touch
//   L0: R=16  S=3 rows=27  ldsbase=0    tbloff=0
//   L1: R=32  S=3 rows=27  ldsbase=27   tbloff=4096
//   L2: R=64  S=4 rows=64  ldsbase=54   tbloff=36864
//   L3: R=128 S=6 rows=216 ldsbase=118  tbloff=299008

template<int R, int S, int BASE, int TOFF>
__device__ __forceinline__ void stage_level(
    const float* __restrict__ emb, float* lds,
    int s0x, int s0y, int s0z, int lane)
{
    const float* tbl = emb + (size_t)TOFF * LEVEL_DIM;
    constexpr int CH = S * S * S * 2;   // 16B chunks
    #pragma unroll
    for (int t0 = 0; t0 < CH; t0 += 64) {
        const int t = t0 + lane;
        if (t < CH) {
            const int row  = t >> 1;
            const int half = (t & 1) * 4;
            const int lx = row % S;
            const int tm = row / S;
            const int ly = tm % S;
            const int lz = tm / S;
            const float* src = tbl +
                ((size_t)((s0z + lz) * R + (s0y + ly)) * R + (s0x + lx)) * LEVEL_DIM + half;
            *(f32x4*)&lds[(BASE + row) * LEVEL_DIM + half] = *(const f32x4*)src;
        }
    }
}

template<int R, int S, int BASE>
__device__ __forceinline__ void enc_level(
    const float* lds, int s0x, int s0y, int s0z,
    float x, float y, float z, float* op)
{
    const float scale = (float)(R - 1);
    const float px = x * scale, py = y * scale, pz = z * scale;
    const float gx = floorf(px), gy = floorf(py), gz = floorf(pz);
    const float fx = px - gx, fy = py - gy, fz = pz - gz;
    const int ix = (int)gx, iy = (int)gy, iz = (int)gz;

    const int ix0 = min(max(ix, 0), R - 1);
    const int ix1 = min(max(ix + 1, 0), R - 1);
    const int iy0 = min(max(iy, 0), R - 1);
    const int iy1 = min(max(iy + 1, 0), R - 1);
    const int iz0 = min(max(iz, 0), R - 1);
    const int iz1 = min(max(iz + 1, 0), R - 1);

    const int lx0 = ix0 - s0x, lx1 = ix1 - s0x;
    const int ly0 = iy0 - s0y, ly1 = iy1 - s0y;
    const int lz0 = iz0 - s0z, lz1 = iz1 - s0z;

    const float wx0 = 1.0f - fx, wx1 = fx;

    float acc[8];
    #pragma unroll
    for (int c = 0; c < 8; ++c) acc[c] = 0.0f;

    #pragma unroll
    for (int kk = 0; kk < 2; ++kk) {
        const int   lz = kk ? lz1 : lz0;
        const float wz = kk ? fz : (1.0f - fz);
        #pragma unroll
        for (int jj = 0; jj < 2; ++jj) {
            const int   ly = jj ? ly1 : ly0;
            const float wy = jj ? fy : (1.0f - fy);

            const int rb = BASE + (lz * S + ly) * S;
            const float* r0 = &lds[(rb + lx0) * LEVEL_DIM];
            const float* r1 = &lds[(rb + lx1) * LEVEL_DIM];

            const float w0 = (wx0 * wy) * wz;
            const float w1 = (wx1 * wy) * wz;

            const f32x4 a0 = *(const f32x4*)(r0);
            const f32x4 a1 = *(const f32x4*)(r0 + 4);
            const f32x4 b0 = *(const f32x4*)(r1);
            const f32x4 b1 = *(const f32x4*)(r1 + 4);

            acc[0] = fmaf(w0, a0.x, acc[0]); acc[1] = fmaf(w0, a0.y, acc[1]);
            acc[2] = fmaf(w0, a0.z, acc[2]); acc[3] = fmaf(w0, a0.w, acc[3]);
            acc[4] = fmaf(w0, a1.x, acc[4]); acc[5] = fmaf(w0, a1.y, acc[5]);
            acc[6] = fmaf(w0, a1.z, acc[6]); acc[7] = fmaf(w0, a1.w, acc[7]);

            acc[0] = fmaf(w1, b0.x, acc[0]); acc[1] = fmaf(w1, b0.y, acc[1]);
            acc[2] = fmaf(w1, b0.z, acc[2]); acc[3] = fmaf(w1, b0.w, acc[3]);
            acc[4] = fmaf(w1, b1.x, acc[4]); acc[5] = fmaf(w1, b1.y, acc[5]);
            acc[6] = fmaf(w1, b1.z, acc[6]); acc[7] = fmaf(w1, b1.w, acc[7]);
        }
    }

    f32x4 lo = { acc[0], acc[1], acc[2], acc[3] };
    f32x4 hi = { acc[4], acc[5], acc[6], acc[7] };
    __builtin_nontemporal_store(lo, (f32x4*)(op));
    __builtin_nontemporal_store(hi, (f32x4*)(op + 4));
}

__global__ __launch_bounds__(64) void nv_encode_cell(
    const float4* __restrict__ sorted,
    const int* __restrict__ offs,       // end-offsets after scatter
    const float* __restrict__ emb,
    float* __restrict__ out)
{
    __shared__ __align__(16) float lds[LDS_ROWS * LEVEL_DIM];

    // XCD-contiguous swizzle: each XCD gets a contiguous z-slab of cells
    int cell = (int)blockIdx.x;
    cell = (cell & 7) * (NCELLS / 8) + (cell >> 3);

    const int lane = threadIdx.x;
    const int start = (cell == 0) ? 0 : offs[cell - 1];
    const int end   = offs[cell];
    if (start >= end) return;   // uniform across the single wave

    const int cx = cell & 31, cy = (cell >> 5) & 31, cz = cell >> 10;

    // stage-base per level: s0 = min(floor(c*scale/32), R - span)  (exact integer)
    const int s0x0 = min((cx * 15) >> 5, 16 - 3);
    const int s0y0 = min((cy * 15) >> 5, 16 - 3);
    const int s0z0 = min((cz * 15) >> 5, 16 - 3);
    const int s0x1 = min((cx * 31) >> 5, 32 - 3);
    const int s0y1 = min((cy * 31) >> 5, 32 - 3);
    const int s0z1 = min((cz * 31) >> 5, 32 - 3);
    const int s0x2 = min((cx * 63) >> 5, 64 - 4);
    const int s0y2 = min((cy * 63) >> 5, 64 - 4);
    const int s0z2 = min((cz * 63) >> 5, 64 - 4);
    const int s0x3 = min((cx * 127) >> 5, 128 - 6);
    const int s0y3 = min((cy * 127) >> 5, 128 - 6);
    const int s0z3 = min((cz * 127) >> 5, 128 - 6);

    stage_level<16,  3, 0,   0>     (emb, lds, s0x0, s0y0, s0z0, lane);
    stage_level<32,  3, 27,  4096>  (emb, lds, s0x1, s0y1, s0z1, lane);
    stage_level<64,  4, 54,  36864> (emb, lds, s0x2, s0y2, s0z2, lane);
    stage_level<128, 6, 118, 299008>(emb, lds, s0x3, s0y3, s0z3, lane);
    __syncthreads();

    for (int p = start + lane; p < end; p += 64) {
        const float4 s = sorted[p];
        const float x = s.x, y = s.y, z = s.z;
        float* op = out + (size_t)__float_as_uint(s.w) * 32;
        enc_level<16,  3, 0>  (lds, s0x0, s0y0, s0z0, x, y, z, op);
        enc_level<32,  3, 27> (lds, s0x1, s0y1, s0z1, x, y, z, op + 8);
        enc_level<64,  4, 54> (lds, s0x2, s0y2, s0z2, x, y, z, op + 16);
        enc_level<128, 6, 118>(lds, s0x3, s0y3, s0z3, x, y, z, op + 24);
    }
}

// ---- fallback direct kernel (ws too small) ----
__global__ __launch_bounds__(256) void nv_encode_direct(
    const float* __restrict__ in,
    const float* __restrict__ emb,
    float* __restrict__ out,
    int B)
{
    const int i = blockIdx.x * 256 + threadIdx.x;
    if (i >= B) return;
    const float x = in[3 * i], y = in[3 * i + 1], z = in[3 * i + 2];
    float* op = out + (size_t)i * 32;

    const int RES[4] = {16, 32, 64, 128};
    const int OFF[4] = {0, 4096, 36864, 299008};

    #pragma unroll
    for (int l = 0; l < 4; ++l) {
        const int R = RES[l];
        const float scale = (float)(R - 1);
        const float px = x * scale, py = y * scale, pz = z * scale;
        const float gx = floorf(px), gy = floorf(py), gz = floorf(pz);
        const float fx = px - gx, fy = py - gy, fz = pz - gz;
        const int ix = (int)gx, iy = (int)gy, iz = (int)gz;
        const int ix0 = min(max(ix, 0), R - 1), ix1 = min(max(ix + 1, 0), R - 1);
        const int iy0 = min(max(iy, 0), R - 1), iy1 = min(max(iy + 1, 0), R - 1);
        const int iz0 = min(max(iz, 0), R - 1), iz1 = min(max(iz + 1, 0), R - 1);
        const float* tbl = emb + (size_t)OFF[l] * LEVEL_DIM;
        const float wx0 = 1.0f - fx, wx1 = fx;
        float acc[8];
        #pragma unroll
        for (int c = 0; c < 8; ++c) acc[c] = 0.0f;
        #pragma unroll
        for (int kk = 0; kk < 2; ++kk) {
            const int zz = kk ? iz1 : iz0;
            const float wz = kk ? fz : (1.0f - fz);
            #pragma unroll
            for (int jj = 0; jj < 2; ++jj) {
                const int yy = jj ? iy1 : iy0;
                const float wy = jj ? fy : (1.0f - fy);
                const size_t rowbase = ((size_t)zz * R + yy) * (size_t)R;
                const float* r0 = tbl + (rowbase + ix0) * LEVEL_DIM;
                const float* r1 = tbl + (rowbase + ix1) * LEVEL_DIM;
                const float w0 = (wx0 * wy) * wz;
                const float w1 = (wx1 * wy) * wz;
                const float4 a0 = *(const float4*)(r0);
                const float4 a1 = *(const float4*)(r0 + 4);
                const float4 b0 = *(const float4*)(r1);
                const float4 b1 = *(const float4*)(r1 + 4);
                acc[0] = fmaf(w0, a0.x, acc[0]); acc[1] = fmaf(w0, a0.y, acc[1]);
                acc[2] = fmaf(w0, a0.z, acc[2]); acc[3] = fmaf(w0, a0.w, acc[3]);
                acc[4] = fmaf(w0, a1.x, acc[4]); acc[5] = fmaf(w0, a1.y, acc[5]);
                acc[6] = fmaf(w0, a1.z, acc[6]); acc[7] = fmaf(w0, a1.w, acc[7]);
                acc[0] = fmaf(w1, b0.x, acc[0]); acc[1] = fmaf(w1, b0.y, acc[1]);
                acc[2] = fmaf(w1, b0.z, acc[2]); acc[3] = fmaf(w1, b0.w, acc[3]);
                acc[4] = fmaf(w1, b1.x, acc[4]); acc[5] = fmaf(w1, b1.y, acc[5]);
                acc[6] = fmaf(w1, b1.z, acc[6]); acc[7] = fmaf(w1, b1.w, acc[7]);
            }
        }
        *(float4*)(op + l * 8)     = make_float4(acc[0], acc[1], acc[2], acc[3]);
        *(float4*)(op + l * 8 + 4) = make_float4(acc[4], acc[5], acc[6], acc[7]);
    }
}

extern "C" void kernel_launch(void* const* d_in, const int* in_sizes, int n_in,
                              void* d_out, int out_size, void* d_ws, size_t ws_size,
                              hipStream_t stream) {
    const float* in  = (const float*)d_in[0];
    const float* emb = (const float*)d_in[1];
    float* out = (float*)d_out;

    const int B = in_sizes[0] / 3;
    const int block = 256;
    const int grid = (B + block - 1) / block;

    const size_t hist_bytes = (size_t)NCELLS * sizeof(int);   // 128 KiB
    const size_t need = hist_bytes + (size_t)B * sizeof(float4);

    if (ws_size >= need) {
        int*    hist   = (int*)d_ws;
        float4* sorted = (float4*)((char*)d_ws + hist_bytes);

        (void)hipMemsetAsync(hist, 0, hist_bytes, stream);
        nv_hist<<<grid, block, 0, stream>>>(in, hist, B);
        nv_scan<<<1, 1024, 0, stream>>>(hist);
        nv_scatter<<<grid, block, 0, stream>>>(in, hist, sorted, B);
        nv_encode_cell<<<NCELLS, 64, 0, stream>>>(sorted, hist, emb, out);
    } else {
        nv_encode_direct<<<grid, block, 0, stream>>>(in, emb, out, B);
    }
}

// Round 5
// 137.018 us; speedup vs baseline: 4.0014x; 2.3965x over previous
//
#include <hip/hip_runtime.h>

#define LEVEL_DIM 8
#define CDIM 32
#define NCELLS (CDIM*CDIM*CDIM)   // 32768 morton-ordered cells
#define NGROUPS (NCELLS/8)        // 4096 groups of 2x2x2 cells

// slab geometry for a 2x2x2-cell group (coverage: s0 = min((2g*(R-1))>>5, R-S))
//   L0: R=16  S=3  rows 27    base 0
//   L1: R=32  S=4  rows 64    base 27
//   L2: R=64  S=6  rows 216   base 91
//   L3: R=128 S=10 rows 1000  base 307
#define SLAB_ROWS 1307            // * 32B = 41824 B

typedef float f32x4 __attribute__((ext_vector_type(4)));

__device__ __forceinline__ unsigned part1by2(unsigned x) {
    x &= 0x3ff;
    x = (x | (x << 16)) & 0x030000FF;
    x = (x | (x << 8))  & 0x0300F00F;
    x = (x | (x << 4))  & 0x030C30C3;
    x = (x | (x << 2))  & 0x09249249;
    return x;
}
__device__ __forceinline__ unsigned compact1by2(unsigned x) {
    x &= 0x09249249;
    x = (x | (x >> 2))  & 0x030C30C3;
    x = (x | (x >> 4))  & 0x0300F00F;
    x = (x | (x >> 8))  & 0x030000FF;
    x = (x | (x >> 16)) & 0x000003FF;
    return x;
}

__device__ __forceinline__ int cell_of(float x, float y, float z) {
    int cx = min(CDIM - 1, max(0, (int)(x * (float)CDIM)));
    int cy = min(CDIM - 1, max(0, (int)(y * (float)CDIM)));
    int cz = min(CDIM - 1, max(0, (int)(z * (float)CDIM)));
    return (int)(part1by2(cx) | (part1by2(cy) << 1) | (part1by2(cz) << 2));
}

__global__ __launch_bounds__(256) void nv_hist(
    const float* __restrict__ in, int* __restrict__ hist,
    unsigned* __restrict__ rank, int B)
{
    const int b = blockIdx.x * 256 + threadIdx.x;
    if (b >= B) return;
    const float x = in[3 * b], y = in[3 * b + 1], z = in[3 * b + 2];
    rank[b] = (unsigned)atomicAdd(&hist[cell_of(x, y, z)], 1);
}

// in-place exclusive scan of NCELLS ints, single workgroup
__global__ __launch_bounds__(1024) void nv_scan(int* __restrict__ cell)
{
    __shared__ int lds[1024];
    const int tid = threadIdx.x;
    const int base = tid * (NCELLS / 1024);   // 32 per thread
    int v[NCELLS / 1024];
    int s = 0;
    #pragma unroll
    for (int e = 0; e < NCELLS / 1024; ++e) { v[e] = cell[base + e]; s += v[e]; }
    lds[tid] = s;
    __syncthreads();
    for (int off = 1; off < 1024; off <<= 1) {
        int t = 0;
        if (tid >= off) t = lds[tid - off];
        __syncthreads();
        if (tid >= off) lds[tid] += t;
        __syncthreads();
    }
    int run = lds[tid] - s;
    #pragma unroll
    for (int e = 0; e < NCELLS / 1024; ++e) { cell[base + e] = run; run += v[e]; }
}

__global__ __launch_bounds__(256) void nv_scatter(
    const float* __restrict__ in, const int* __restrict__ starts,
    const unsigned* __restrict__ rank, float4* __restrict__ sorted, int B)
{
    const int b = blockIdx.x * 256 + threadIdx.x;
    if (b >= B) return;
    const float x = in[3 * b], y = in[3 * b + 1], z = in[3 * b + 2];
    const int pos = starts[cell_of(x, y, z)] + (int)rank[b];
    sorted[pos] = make_float4(x, y, z, __uint_as_float((unsigned)b));
}

// ---- group encode ----

template<int R, int S, int BASE, int TOFF>
__device__ __forceinline__ void stage_level(
    const float* __restrict__ emb, float* slab,
    int s0x, int s0y, int s0z, int tid)
{
    const float* tbl = emb + (size_t)TOFF * LEVEL_DIM;
    constexpr int CH = S * S * S * 2;     // 16B chunks
    #pragma unroll
    for (int t0 = 0; t0 < CH; t0 += 256) {
        const int t = t0 + tid;
        if (t < CH) {
            const int row  = t >> 1;
            const int half = (t & 1) * 4;
            const int lx = row % S;
            const int tm = row / S;
            const int ly = tm % S;
            const int lz = tm / S;
            const float* src = tbl +
                ((size_t)((s0z + lz) * R + (s0y + ly)) * R + (s0x + lx)) * LEVEL_DIM + half;
            *(f32x4*)&slab[(BASE + row) * LEVEL_DIM + half] = *(const f32x4*)src;
        }
    }
}

template<int R, int S, int BASE>
__device__ __forceinline__ void enc_level(
    const float* slab, int s0x, int s0y, int s0z,
    float x, float y, float z, float* accp)
{
    const float scale = (float)(R - 1);
    const float px = x * scale, py = y * scale, pz = z * scale;
    const float gx = floorf(px), gy = floorf(py), gz = floorf(pz);
    const float fx = px - gx, fy = py - gy, fz = pz - gz;
    const int ix = (int)gx, iy = (int)gy, iz = (int)gz;

    const int ix0 = min(max(ix, 0), R - 1);
    const int ix1 = min(max(ix + 1, 0), R - 1);
    const int iy0 = min(max(iy, 0), R - 1);
    const int iy1 = min(max(iy + 1, 0), R - 1);
    const int iz0 = min(max(iz, 0), R - 1);
    const int iz1 = min(max(iz + 1, 0), R - 1);

    const int lx0 = ix0 - s0x, lx1 = ix1 - s0x;
    const int ly0 = iy0 - s0y, ly1 = iy1 - s0y;
    const int lz0 = iz0 - s0z, lz1 = iz1 - s0z;

    const float wx0 = 1.0f - fx, wx1 = fx;

    float acc[8];
    #pragma unroll
    for (int c = 0; c < 8; ++c) acc[c] = 0.0f;

    #pragma unroll
    for (int kk = 0; kk < 2; ++kk) {
        const int   lz = kk ? lz1 : lz0;
        const float wz = kk ? fz : (1.0f - fz);
        #pragma unroll
        for (int jj = 0; jj < 2; ++jj) {
            const int   ly = jj ? ly1 : ly0;
            const float wy = jj ? fy : (1.0f - fy);

            const int rb = BASE + (lz * S + ly) * S;
            const float* r0 = &slab[(rb + lx0) * LEVEL_DIM];
            const float* r1 = &slab[(rb + lx1) * LEVEL_DIM];

            const float w0 = (wx0 * wy) * wz;
            const float w1 = (wx1 * wy) * wz;

            const f32x4 a0 = *(const f32x4*)(r0);
            const f32x4 a1 = *(const f32x4*)(r0 + 4);
            const f32x4 b0 = *(const f32x4*)(r1);
            const f32x4 b1 = *(const f32x4*)(r1 + 4);

            acc[0] = fmaf(w0, a0.x, acc[0]); acc[1] = fmaf(w0, a0.y, acc[1]);
            acc[2] = fmaf(w0, a0.z, acc[2]); acc[3] = fmaf(w0, a0.w, acc[3]);
            acc[4] = fmaf(w0, a1.x, acc[4]); acc[5] = fmaf(w0, a1.y, acc[5]);
            acc[6] = fmaf(w0, a1.z, acc[6]); acc[7] = fmaf(w0, a1.w, acc[7]);

            acc[0] = fmaf(w1, b0.x, acc[0]); acc[1] = fmaf(w1, b0.y, acc[1]);
            acc[2] = fmaf(w1, b0.z, acc[2]); acc[3] = fmaf(w1, b0.w, acc[3]);
            acc[4] = fmaf(w1, b1.x, acc[4]); acc[5] = fmaf(w1, b1.y, acc[5]);
            acc[6] = fmaf(w1, b1.z, acc[6]); acc[7] = fmaf(w1, b1.w, acc[7]);
        }
    }
    #pragma unroll
    for (int c = 0; c < 8; ++c) accp[c] = acc[c];
}

__global__ __launch_bounds__(256) void nv_encode_group(
    const float4* __restrict__ sorted,
    const int* __restrict__ starts,     // exclusive cell starts (unmutated)
    const float* __restrict__ emb,
    float* __restrict__ out,
    int B)
{
    __shared__ __align__(16) float slab[SLAB_ROWS * LEVEL_DIM];  // 41824 B
    __shared__ __align__(16) float obuf[4][16 * 36];             // 9216 B, 144B rows (pad)

    // XCD swizzle: each XCD gets a contiguous morton octant of groups
    int grp = (int)blockIdx.x;
    grp = (grp & 7) * (NGROUPS / 8) + (grp >> 3);

    const int c0 = grp << 3;
    const int start = starts[c0];
    const int end   = (c0 + 8 < NCELLS) ? starts[c0 + 8] : B;
    if (start >= end) return;

    const int gx = (int)compact1by2((unsigned)grp);
    const int gy = (int)compact1by2((unsigned)grp >> 1);
    const int gz = (int)compact1by2((unsigned)grp >> 2);

    // slab bases per level: s0 = min((2g*(R-1))>>5, R-S)
    const int s0x0 = min((gx * 30)  >> 5, 13),  s0y0 = min((gy * 30)  >> 5, 13),  s0z0 = min((gz * 30)  >> 5, 13);
    const int s0x1 = min((gx * 62)  >> 5, 28),  s0y1 = min((gy * 62)  >> 5, 28),  s0z1 = min((gz * 62)  >> 5, 28);
    const int s0x2 = min((gx * 126) >> 5, 58),  s0y2 = min((gy * 126) >> 5, 58),  s0z2 = min((gz * 126) >> 5, 58);
    const int s0x3 = min((gx * 254) >> 5, 118), s0y3 = min((gy * 254) >> 5, 118), s0z3 = min((gz * 254) >> 5, 118);

    const int tid = threadIdx.x;
    stage_level<16,  3,  0,   0>     (emb, slab, s0x0, s0y0, s0z0, tid);
    stage_level<32,  4,  27,  4096>  (emb, slab, s0x1, s0y1, s0z1, tid);
    stage_level<64,  6,  91,  36864> (emb, slab, s0x2, s0y2, s0z2, tid);
    stage_level<128, 10, 307, 299008>(emb, slab, s0x3, s0y3, s0z3, tid);
    __syncthreads();

    const int wave = tid >> 6;
    const int lane = tid & 63;
    float* wbuf = &obuf[wave][0];

    for (int p0 = start + wave * 64; p0 < end; p0 += 256) {
        const int p = p0 + lane;
        const bool valid = p < end;

        float acc[32];
        unsigned ob = 0;
        if (valid) {
            const float4 s = sorted[p];
            ob = __float_as_uint(s.w);
            enc_level<16,  3,  0>  (slab, s0x0, s0y0, s0z0, s.x, s.y, s.z, &acc[0]);
            enc_level<32,  4,  27> (slab, s0x1, s0y1, s0z1, s.x, s.y, s.z, &acc[8]);
            enc_level<64,  6,  91> (slab, s0x2, s0y2, s0z2, s.x, s.y, s.z, &acc[16]);
            enc_level<128, 10, 307>(slab, s0x3, s0y3, s0z3, s.x, s.y, s.z, &acc[24]);
        }

        // transpose 16 points/pass through LDS; store with 8 lanes per point
        #pragma unroll
        for (int pass = 0; pass < 4; ++pass) {
            // WAR guard vs previous pass's reads
            asm volatile("s_waitcnt lgkmcnt(0)" ::: "memory");
            if (valid && (lane >> 4) == pass) {
                const int q = lane & 15;
                #pragma unroll
                for (int k = 0; k < 8; ++k)
                    *(f32x4*)&wbuf[q * 36 + k * 4] = *(const f32x4*)&acc[k * 4];
            }
            asm volatile("s_waitcnt lgkmcnt(0)" ::: "memory");
            #pragma unroll
            for (int j = 0; j < 2; ++j) {
                const int i = pass * 16 + j * 8 + (lane >> 3);   // point slot in wave
                const unsigned obi = __shfl(ob, i);
                if (p0 + i < end) {
                    const f32x4 v = *(const f32x4*)
                        &wbuf[(i - pass * 16) * 36 + (lane & 7) * 4];
                    __builtin_nontemporal_store(
                        v, (f32x4*)(out + (size_t)obi * 32 + (lane & 7) * 4));
                }
            }
        }
    }
}

// ---- fallback direct kernel (ws too small) ----
__global__ __launch_bounds__(256) void nv_encode_direct(
    const float* __restrict__ in,
    const float* __restrict__ emb,
    float* __restrict__ out,
    int B)
{
    const int i = blockIdx.x * 256 + threadIdx.x;
    if (i >= B) return;
    const float x = in[3 * i], y = in[3 * i + 1], z = in[3 * i + 2];
    float* op = out + (size_t)i * 32;

    const int RES[4] = {16, 32, 64, 128};
    const int OFF[4] = {0, 4096, 36864, 299008};

    #pragma unroll
    for (int l = 0; l < 4; ++l) {
        const int R = RES[l];
        const float scale = (float)(R - 1);
        const float px = x * scale, py = y * scale, pz = z * scale;
        const float gxf = floorf(px), gyf = floorf(py), gzf = floorf(pz);
        const float fx = px - gxf, fy = py - gyf, fz = pz - gzf;
        const int ix = (int)gxf, iy = (int)gyf, iz = (int)gzf;
        const int ix0 = min(max(ix, 0), R - 1), ix1 = min(max(ix + 1, 0), R - 1);
        const int iy0 = min(max(iy, 0), R - 1), iy1 = min(max(iy + 1, 0), R - 1);
        const int iz0 = min(max(iz, 0), R - 1), iz1 = min(max(iz + 1, 0), R - 1);
        const float* tbl = emb + (size_t)OFF[l] * LEVEL_DIM;
        const float wx0 = 1.0f - fx, wx1 = fx;
        float acc[8];
        #pragma unroll
        for (int c = 0; c < 8; ++c) acc[c] = 0.0f;
        #pragma unroll
        for (int kk = 0; kk < 2; ++kk) {
            const int zz = kk ? iz1 : iz0;
            const float wz = kk ? fz : (1.0f - fz);
            #pragma unroll
            for (int jj = 0; jj < 2; ++jj) {
                const int yy = jj ? iy1 : iy0;
                const float wy = jj ? fy : (1.0f - fy);
                const size_t rowbase = ((size_t)zz * R + yy) * (size_t)R;
                const float* r0 = tbl + (rowbase + ix0) * LEVEL_DIM;
                const float* r1 = tbl + (rowbase + ix1) * LEVEL_DIM;
                const float w0 = (wx0 * wy) * wz;
                const float w1 = (wx1 * wy) * wz;
                const float4 a0 = *(const float4*)(r0);
                const float4 a1 = *(const float4*)(r0 + 4);
                const float4 b0 = *(const float4*)(r1);
                const float4 b1 = *(const float4*)(r1 + 4);
                acc[0] = fmaf(w0, a0.x, acc[0]); acc[1] = fmaf(w0, a0.y, acc[1]);
                acc[2] = fmaf(w0, a0.z, acc[2]); acc[3] = fmaf(w0, a0.w, acc[3]);
                acc[4] = fmaf(w0, a1.x, acc[4]); acc[5] = fmaf(w0, a1.y, acc[5]);
                acc[6] = fmaf(w0, a1.z, acc[6]); acc[7] = fmaf(w0, a1.w, acc[7]);
                acc[0] = fmaf(w1, b0.x, acc[0]); acc[1] = fmaf(w1, b0.y, acc[1]);
                acc[2] = fmaf(w1, b0.z, acc[2]); acc[3] = fmaf(w1, b0.w, acc[3]);
                acc[4] = fmaf(w1, b1.x, acc[4]); acc[5] = fmaf(w1, b1.y, acc[5]);
                acc[6] = fmaf(w1, b1.z, acc[6]); acc[7] = fmaf(w1, b1.w, acc[7]);
            }
        }
        *(float4*)(op + l * 8)     = make_float4(acc[0], acc[1], acc[2], acc[3]);
        *(float4*)(op + l * 8 + 4) = make_float4(acc[4], acc[5], acc[6], acc[7]);
    }
}

extern "C" void kernel_launch(void* const* d_in, const int* in_sizes, int n_in,
                              void* d_out, int out_size, void* d_ws, size_t ws_size,
                              hipStream_t stream) {
    const float* in  = (const float*)d_in[0];
    const float* emb = (const float*)d_in[1];
    float* out = (float*)d_out;

    const int B = in_sizes[0] / 3;
    const int block = 256;
    const int grid = (B + block - 1) / block;

    const size_t hist_bytes = (size_t)NCELLS * sizeof(int);        // 128 KiB
    const size_t rank_bytes = (size_t)B * sizeof(unsigned);        // 4 MiB
    const size_t need = hist_bytes + rank_bytes + (size_t)B * sizeof(float4);

    if (ws_size >= need) {
        int*      hist   = (int*)d_ws;                                    // -> starts after scan
        unsigned* rank   = (unsigned*)((char*)d_ws + hist_bytes);
        float4*   sorted = (float4*)((char*)d_ws + hist_bytes + rank_bytes);

        (void)hipMemsetAsync(hist, 0, hist_bytes, stream);
        nv_hist<<<grid, block, 0, stream>>>(in, hist, rank, B);
        nv_scan<<<1, 1024, 0, stream>>>(hist);
        nv_scatter<<<grid, block, 0, stream>>>(in, hist, rank, sorted, B);
        nv_encode_group<<<NGROUPS, 256, 0, stream>>>(sorted, hist, emb, out, B);
    } else {
        nv_encode_direct<<<grid, block, 0, stream>>>(in, emb, out, B);
    }
}